// Round 1
// baseline (563.887 us; speedup 1.0000x reference)
//
#include <hip/hip_runtime.h>
#include <hip/hip_bf16.h>

#define T_TOK 4096
#define DM 1024
#define DH 4096
#define NE 8

typedef __attribute__((ext_vector_type(4))) float fl4;
typedef __attribute__((ext_vector_type(8))) short sh8;
typedef __attribute__((ext_vector_type(8))) unsigned short us8;
typedef unsigned short u16;

// ---------------- workspace layout (bytes) ----------------
#define XBF_OFF   ((size_t)0)
#define XBF_BYTES ((size_t)T_TOK * DM * 2)            // x in bf16: 8 MB
#define H_OFF     (XBF_OFF + XBF_BYTES)
#define H_ROWS    (T_TOK * 2 + 128)                    // 8320 slots (incl. pad)
#define H_BYTES   ((size_t)H_ROWS * DH * 2)            // 65 MB
#define TOKMAP_OFF (H_OFF + H_BYTES)
#define PAIRW_OFF  (TOKMAP_OFF + (size_t)H_ROWS * 4)
#define TOKE_OFF   (PAIRW_OFF + (size_t)H_ROWS * 4)
#define TOKW_OFF   (TOKE_OFF + (size_t)T_TOK * 2 * 4)
#define CTL_OFF    (TOKW_OFF + (size_t)T_TOK * 2 * 4)
// ctl: [0..7]=counts, [8..15]=cursor, [16..23]=bases

__device__ __forceinline__ u16 f2bf(float f) {
  __hip_bfloat16 h = __float2bfloat16(f);
  return __builtin_bit_cast(u16, h);
}

__device__ __forceinline__ float gelu_tanh(float x) {
  float x3 = x * x * x;
  float u = 0.7978845608028654f * (x + 0.044715f * x3);
  return 0.5f * x * (1.0f + tanhf(u));
}

__device__ __forceinline__ void gload_lds16(const void* g, void* l) {
  __builtin_amdgcn_global_load_lds(
      (const __attribute__((address_space(1))) unsigned int*)g,
      (__attribute__((address_space(3))) unsigned int*)l, 16, 0, 0);
}

// ---------------- router: logits, top-2, softmax, counts, x->bf16 ----------------
__global__ __launch_bounds__(256) void router_kernel(
    const float* __restrict__ x, const float* __restrict__ rw,
    u16* __restrict__ xbf, int* __restrict__ tok_e, float* __restrict__ tok_w,
    int* __restrict__ ctl) {
  int tid = threadIdx.x;
  int wv = tid >> 6, lane = tid & 63;
  int t = blockIdx.x * 4 + wv;
  if (t >= T_TOK) return;

  const float* xp = x + (size_t)t * DM + lane * 16;
  fl4 xq[4];
#pragma unroll
  for (int i = 0; i < 4; i++) xq[i] = *(const fl4*)(xp + i * 4);

  float acc8[NE];
#pragma unroll
  for (int e = 0; e < NE; e++) {
    const float* wp = rw + (size_t)e * DM + lane * 16;
    float s = 0.f;
#pragma unroll
    for (int i = 0; i < 4; i++) {
      fl4 w4 = *(const fl4*)(wp + i * 4);
      s += xq[i][0] * w4[0] + xq[i][1] * w4[1] + xq[i][2] * w4[2] + xq[i][3] * w4[3];
    }
    acc8[e] = s;
  }
  // bf16 copy of x (coalesced 16B stores)
  us8 h0, h1;
#pragma unroll
  for (int i = 0; i < 8; i++) {
    h0[i] = f2bf(xq[i >> 2][i & 3]);
    h1[i] = f2bf(xq[2 + (i >> 2)][i & 3]);
  }
  *(us8*)(xbf + (size_t)t * DM + lane * 16) = h0;
  *(us8*)(xbf + (size_t)t * DM + lane * 16 + 8) = h1;

  // full-wave reduction for the 8 logits
#pragma unroll
  for (int e = 0; e < NE; e++) {
#pragma unroll
    for (int off = 32; off > 0; off >>= 1) acc8[e] += __shfl_xor(acc8[e], off);
  }

  if (lane == 0) {
    float v1 = -1e30f, v2 = -1e30f;
    int i1 = 0, i2 = 0;
#pragma unroll
    for (int e = 0; e < NE; e++) {
      float v = acc8[e];
      if (v > v1) { v2 = v1; i2 = i1; v1 = v; i1 = e; }
      else if (v > v2) { v2 = v; i2 = e; }
    }
    float ex = expf(v2 - v1);
    float s = 1.0f + ex;
    tok_e[t * 2] = i1; tok_e[t * 2 + 1] = i2;
    tok_w[t * 2] = 1.0f / s; tok_w[t * 2 + 1] = ex / s;
    atomicAdd(&ctl[i1], 1);
    atomicAdd(&ctl[i2], 1);
  }
}

__global__ void scan_kernel(int* __restrict__ ctl) {
  if (threadIdx.x == 0 && blockIdx.x == 0) {
    int s = 0;
    for (int e = 0; e < NE; e++) {
      int c = ctl[e];
      ctl[16 + e] = s;  // base
      ctl[8 + e] = s;   // cursor
      s += c;
    }
  }
}

__global__ __launch_bounds__(256) void assign_kernel(
    const int* __restrict__ tok_e, const float* __restrict__ tok_w,
    int* __restrict__ ctl, int* __restrict__ tok_map, float* __restrict__ pair_w) {
  int t = blockIdx.x * 256 + threadIdx.x;
  if (t < T_TOK) {
#pragma unroll
    for (int k = 0; k < 2; k++) {
      int e = tok_e[t * 2 + k];
      int slot = atomicAdd(&ctl[8 + e], 1);
      tok_map[slot] = t;
      pair_w[slot] = tok_w[t * 2 + k];
    }
  } else if (t < T_TOK + 128) {
    tok_map[T_TOK * 2 + (t - T_TOK)] = 0;
    pair_w[T_TOK * 2 + (t - T_TOK)] = 0.f;
  }
}

// ---------------- grouped GEMM (128x128 tile, BK=32, 4 waves) ----------------
// FC1: A = xbf gathered by tok_map [cnt x 1024] bf16, B = fc1_w[e] [4096 x 1024] fp32
//      out: H[slot][col] = gelu(A.B^T + b1)  (bf16)
// FC2: A = H rows [cnt x 4096] bf16, B = fc2_w[e] [1024 x 4096] fp32
//      out: atomicAdd(out[tok][col], w * (A.B^T + b2))
template <bool FC1>
__global__ __launch_bounds__(256) void moe_gemm(
    const u16* __restrict__ Abase, const float* __restrict__ Wall,
    const float* __restrict__ bias, u16* __restrict__ Hout,
    float* __restrict__ Out, const int* __restrict__ tok_map,
    const float* __restrict__ pair_w, const int* __restrict__ ctl) {
  constexpr int KTOT = FC1 ? DM : DH;
  constexpr int NTOT = FC1 ? DH : DM;
  constexpr int NT = NTOT / 128;
  constexpr int MT = 32;  // worst-case 4096/128

  int bid = blockIdx.x;
  int e = bid / (MT * NT);
  int r = bid - e * (MT * NT);
  int mt = r / NT, nt = r - mt * NT;
  int base = ctl[16 + e], cnt = ctl[e];
  if (mt * 128 >= cnt) return;

  __shared__ u16 As[128 * 32];    // bf16 tile, xor-swizzled (16B granule, row&3)
  __shared__ float Bs[128 * 32];  // fp32 tile, xor-swizzled (16B granule, row&7)

  int tid = threadIdx.x;
  int wv = tid >> 6, lane = tid & 63;
  int wr = wv >> 1, wc = wv & 1;
  int khalf = lane >> 4, l15 = lane & 15;

  // A staging source addrs (2 x 16B chunks per thread), swizzle folded in
  const u16* asrc[2];
#pragma unroll
  for (int r2 = 0; r2 < 2; r2++) {
    int c = r2 * 256 + tid;
    int row = c >> 2, q = c & 3;
    int qs = q ^ (row & 3);
    int grow = base + mt * 128 + row;
    size_t arow = FC1 ? (size_t)tok_map[grow] : (size_t)grow;
    asrc[r2] = Abase + arow * KTOT + qs * 8;
  }
  // B staging source addrs (4 x 16B chunks per thread)
  const float* bsrc[4];
#pragma unroll
  for (int r4 = 0; r4 < 4; r4++) {
    int c = r4 * 256 + tid;
    int row = c >> 3, f = c & 7;
    int fs = f ^ (row & 7);
    bsrc[r4] = Wall + ((size_t)e * NTOT + nt * 128 + row) * KTOT + fs * 4;
  }

  fl4 acc[4][4];
#pragma unroll
  for (int m = 0; m < 4; m++)
#pragma unroll
    for (int n = 0; n < 4; n++) acc[m][n] = (fl4){0.f, 0.f, 0.f, 0.f};

  for (int kt = 0; kt < KTOT / 32; ++kt) {
#pragma unroll
    for (int r2 = 0; r2 < 2; r2++)
      gload_lds16(asrc[r2] + kt * 32, &As[(r2 * 256 + wv * 64) * 8]);
#pragma unroll
    for (int r4 = 0; r4 < 4; r4++)
      gload_lds16(bsrc[r4] + kt * 32, &Bs[(r4 * 256 + wv * 64) * 4]);
    __syncthreads();

    sh8 af[4], bfr[4];
#pragma unroll
    for (int m = 0; m < 4; m++) {
      int rowl = wr * 64 + m * 16 + l15;
      int off = rowl * 64 + ((khalf * 16) ^ ((rowl & 3) << 4));
      af[m] = *(const sh8*)((const char*)As + off);
    }
#pragma unroll
    for (int n = 0; n < 4; n++) {
      int coll = wc * 64 + n * 16 + l15;
      int o0 = coll * 128 + ((khalf * 32) ^ ((coll & 7) << 4));
      int o1 = coll * 128 + ((khalf * 32 + 16) ^ ((coll & 7) << 4));
      fl4 b0 = *(const fl4*)((const char*)Bs + o0);
      fl4 b1 = *(const fl4*)((const char*)Bs + o1);
      sh8 bv;
#pragma unroll
      for (int i = 0; i < 4; i++) {
        bv[i] = (short)f2bf(b0[i]);
        bv[i + 4] = (short)f2bf(b1[i]);
      }
      bfr[n] = bv;
    }
#pragma unroll
    for (int m = 0; m < 4; m++)
#pragma unroll
      for (int n = 0; n < 4; n++)
        acc[m][n] = __builtin_amdgcn_mfma_f32_16x16x32_bf16(af[m], bfr[n], acc[m][n], 0, 0, 0);
    __syncthreads();
  }

  if (FC1) {
#pragma unroll
    for (int n = 0; n < 4; n++) {
      int colg = nt * 128 + wc * 64 + n * 16 + l15;
      float bn = bias[(size_t)e * DH + colg];
#pragma unroll
      for (int m = 0; m < 4; m++) {
#pragma unroll
        for (int j = 0; j < 4; j++) {
          int grow = mt * 128 + wr * 64 + m * 16 + khalf * 4 + j;
          if (grow < cnt) {
            float v = acc[m][n][j] + bn;
            Hout[(size_t)(base + grow) * DH + colg] = f2bf(gelu_tanh(v));
          }
        }
      }
    }
  } else {
#pragma unroll
    for (int m = 0; m < 4; m++) {
#pragma unroll
      for (int j = 0; j < 4; j++) {
        int grow = mt * 128 + wr * 64 + m * 16 + khalf * 4 + j;
        if (grow < cnt) {
          int slot = base + grow;
          int t = tok_map[slot];
          float w = pair_w[slot];
#pragma unroll
          for (int n = 0; n < 4; n++) {
            int colg = nt * 128 + wc * 64 + n * 16 + l15;
            float v = acc[m][n][j] + bias[(size_t)e * DM + colg];
            atomicAdd(&Out[(size_t)t * DM + colg], w * v);
          }
        }
      }
    }
  }
}

extern "C" void kernel_launch(void* const* d_in, const int* in_sizes, int n_in,
                              void* d_out, int out_size, void* d_ws, size_t ws_size,
                              hipStream_t stream) {
  const float* x  = (const float*)d_in[0];
  const float* rw = (const float*)d_in[1];
  const float* w1 = (const float*)d_in[2];
  const float* b1 = (const float*)d_in[3];
  const float* w2 = (const float*)d_in[4];
  const float* b2 = (const float*)d_in[5];
  float* out = (float*)d_out;

  char* ws = (char*)d_ws;
  u16* xbf      = (u16*)(ws + XBF_OFF);
  u16* H        = (u16*)(ws + H_OFF);
  int* tok_map  = (int*)(ws + TOKMAP_OFF);
  float* pair_w = (float*)(ws + PAIRW_OFF);
  int* tok_e    = (int*)(ws + TOKE_OFF);
  float* tok_w  = (float*)(ws + TOKW_OFF);
  int* ctl      = (int*)(ws + CTL_OFF);

  hipMemsetAsync(out, 0, (size_t)T_TOK * DM * 4, stream);
  hipMemsetAsync(ctl, 0, 24 * 4, stream);

  router_kernel<<<T_TOK / 4, 256, 0, stream>>>(x, rw, xbf, tok_e, tok_w, ctl);
  scan_kernel<<<1, 64, 0, stream>>>(ctl);
  assign_kernel<<<(T_TOK + 128 + 255) / 256, 256, 0, stream>>>(tok_e, tok_w, ctl, tok_map, pair_w);
  moe_gemm<true><<<NE * 32 * (DH / 128), 256, 0, stream>>>(
      xbf, w1, b1, H, nullptr, tok_map, pair_w, ctl);
  moe_gemm<false><<<NE * 32 * (DM / 128), 256, 0, stream>>>(
      H, w2, b2, nullptr, out, tok_map, pair_w, ctl);
}

// Round 2
// 520.023 us; speedup vs baseline: 1.0843x; 1.0843x over previous
//
#include <hip/hip_runtime.h>
#include <hip/hip_bf16.h>

#define T_TOK 4096
#define DM 1024
#define DH 4096
#define NE 8
#define H_ROWS (T_TOK * 2 + 128)
#define WELEMS ((size_t)NE * DH * DM)  // 33,554,432 per weight tensor

typedef __attribute__((ext_vector_type(4))) float fl4;
typedef __attribute__((ext_vector_type(8))) short sh8;
typedef __attribute__((ext_vector_type(8))) unsigned short us8;
typedef unsigned short u16;

__device__ __forceinline__ u16 f2bf(float f) {
  __hip_bfloat16 h = __float2bfloat16(f);
  return __builtin_bit_cast(u16, h);
}

__device__ __forceinline__ float gelu_tanh(float x) {
  float x3 = x * x * x;
  float u = 0.7978845608028654f * (x + 0.044715f * x3);
  return 0.5f * x * (1.0f + tanhf(u));
}

__device__ __forceinline__ void gload_lds16(const void* g, void* l) {
  __builtin_amdgcn_global_load_lds(
      (const __attribute__((address_space(1))) unsigned int*)g,
      (__attribute__((address_space(3))) unsigned int*)l, 16, 0, 0);
}

// ---------------- weight fp32 -> bf16 convert (HBM-bound) ----------------
__global__ __launch_bounds__(256) void wconv_kernel(
    const float* __restrict__ w1, const float* __restrict__ w2,
    u16* __restrict__ w1b, u16* __restrict__ w2b) {
  size_t stride = (size_t)gridDim.x * 256 * 8;
  for (size_t i = ((size_t)blockIdx.x * 256 + threadIdx.x) * 8; i < WELEMS; i += stride) {
    fl4 a0 = *(const fl4*)(w1 + i);
    fl4 a1 = *(const fl4*)(w1 + i + 4);
    fl4 b0 = *(const fl4*)(w2 + i);
    fl4 b1 = *(const fl4*)(w2 + i + 4);
    us8 oa, ob;
#pragma unroll
    for (int j = 0; j < 4; j++) {
      oa[j] = f2bf(a0[j]); oa[j + 4] = f2bf(a1[j]);
      ob[j] = f2bf(b0[j]); ob[j + 4] = f2bf(b1[j]);
    }
    *(us8*)(w1b + i) = oa;
    *(us8*)(w2b + i) = ob;
  }
}

// ---------------- router: logits, top-2, softmax, counts, x->bf16 ----------------
__global__ __launch_bounds__(256) void router_kernel(
    const float* __restrict__ x, const float* __restrict__ rw,
    u16* __restrict__ xbf, int* __restrict__ tok_e, float* __restrict__ tok_w,
    int* __restrict__ ctl) {
  int tid = threadIdx.x;
  int wv = tid >> 6, lane = tid & 63;
  int t = blockIdx.x * 4 + wv;
  if (t >= T_TOK) return;

  const float* xp = x + (size_t)t * DM + lane * 16;
  fl4 xq[4];
#pragma unroll
  for (int i = 0; i < 4; i++) xq[i] = *(const fl4*)(xp + i * 4);

  float acc8[NE];
#pragma unroll
  for (int e = 0; e < NE; e++) {
    const float* wp = rw + (size_t)e * DM + lane * 16;
    float s = 0.f;
#pragma unroll
    for (int i = 0; i < 4; i++) {
      fl4 w4 = *(const fl4*)(wp + i * 4);
      s += xq[i][0] * w4[0] + xq[i][1] * w4[1] + xq[i][2] * w4[2] + xq[i][3] * w4[3];
    }
    acc8[e] = s;
  }
  us8 h0, h1;
#pragma unroll
  for (int i = 0; i < 8; i++) {
    h0[i] = f2bf(xq[i >> 2][i & 3]);
    h1[i] = f2bf(xq[2 + (i >> 2)][i & 3]);
  }
  *(us8*)(xbf + (size_t)t * DM + lane * 16) = h0;
  *(us8*)(xbf + (size_t)t * DM + lane * 16 + 8) = h1;

#pragma unroll
  for (int e = 0; e < NE; e++) {
#pragma unroll
    for (int off = 32; off > 0; off >>= 1) acc8[e] += __shfl_xor(acc8[e], off);
  }

  if (lane == 0) {
    float v1 = -1e30f, v2 = -1e30f;
    int i1 = 0, i2 = 0;
#pragma unroll
    for (int e = 0; e < NE; e++) {
      float v = acc8[e];
      if (v > v1) { v2 = v1; i2 = i1; v1 = v; i1 = e; }
      else if (v > v2) { v2 = v; i2 = e; }
    }
    float ex = expf(v2 - v1);
    float s = 1.0f + ex;
    tok_e[t * 2] = i1; tok_e[t * 2 + 1] = i2;
    tok_w[t * 2] = 1.0f / s; tok_w[t * 2 + 1] = ex / s;
    atomicAdd(&ctl[i1], 1);
    atomicAdd(&ctl[i2], 1);
  }
}

__global__ void scan_kernel(int* __restrict__ ctl) {
  if (threadIdx.x == 0 && blockIdx.x == 0) {
    int s = 0;
    for (int e = 0; e < NE; e++) {
      int c = ctl[e];
      ctl[16 + e] = s;
      ctl[8 + e] = s;
      s += c;
    }
  }
}

__global__ __launch_bounds__(256) void assign_kernel(
    const int* __restrict__ tok_e, const float* __restrict__ tok_w,
    int* __restrict__ ctl, int* __restrict__ tok_map, float* __restrict__ pair_w) {
  int t = blockIdx.x * 256 + threadIdx.x;
  if (t < T_TOK) {
#pragma unroll
    for (int k = 0; k < 2; k++) {
      int e = tok_e[t * 2 + k];
      int slot = atomicAdd(&ctl[8 + e], 1);
      tok_map[slot] = t;
      pair_w[slot] = tok_w[t * 2 + k];
    }
  } else if (t < T_TOK + 128) {
    tok_map[T_TOK * 2 + (t - T_TOK)] = 0;
    pair_w[T_TOK * 2 + (t - T_TOK)] = 0.f;
  }
}

// ---------------- grouped GEMM (128x128 tile, BK=32, 4 waves) ----------------
// WB=true: B operand pre-converted bf16 (8KB tile). WB=false: fp32 B, cvt in-loop.
template <bool FC1, bool WB>
__global__ __launch_bounds__(256) void moe_gemm(
    const u16* __restrict__ Abase, const float* __restrict__ Wf,
    const u16* __restrict__ Wb, const float* __restrict__ bias,
    u16* __restrict__ Hout, float* __restrict__ Out,
    const int* __restrict__ tok_map, const float* __restrict__ pair_w,
    const int* __restrict__ ctl) {
  constexpr int KTOT = FC1 ? DM : DH;
  constexpr int NTOT = FC1 ? DH : DM;
  constexpr int NT = NTOT / 128;
  constexpr int MT = 32;

  int bid = blockIdx.x;
  int e = bid / (MT * NT);
  int r = bid - e * (MT * NT);
  int mt = r / NT, nt = r - mt * NT;
  int base = ctl[16 + e], cnt = ctl[e];
  if (mt * 128 >= cnt) return;

  __shared__ u16 As[128 * 32];
  __shared__ char Braw[WB ? 128 * 32 * 2 : 128 * 32 * 4];

  int tid = threadIdx.x;
  int wv = tid >> 6, lane = tid & 63;
  int wr = wv >> 1, wc = wv & 1;
  int khalf = lane >> 4, l15 = lane & 15;

  // A staging (bf16, 2 x 16B chunks/thread), swizzle pre-folded into global src
  const u16* asrc[2];
#pragma unroll
  for (int r2 = 0; r2 < 2; r2++) {
    int c = r2 * 256 + tid;
    int row = c >> 2, q = c & 3;
    int qs = q ^ (row & 3);
    int grow = base + mt * 128 + row;
    size_t arow = FC1 ? (size_t)tok_map[grow] : (size_t)grow;
    asrc[r2] = Abase + arow * KTOT + qs * 8;
  }
  // B staging
  const u16* bsrcb[2];
  const float* bsrcf[4];
  if constexpr (WB) {
#pragma unroll
    for (int r2 = 0; r2 < 2; r2++) {
      int c = r2 * 256 + tid;
      int row = c >> 2, q = c & 3;
      int qs = q ^ (row & 3);
      bsrcb[r2] = Wb + ((size_t)e * NTOT + nt * 128 + row) * KTOT + qs * 8;
    }
  } else {
#pragma unroll
    for (int r4 = 0; r4 < 4; r4++) {
      int c = r4 * 256 + tid;
      int row = c >> 3, f = c & 7;
      int fs = f ^ (row & 7);
      bsrcf[r4] = Wf + ((size_t)e * NTOT + nt * 128 + row) * KTOT + fs * 4;
    }
  }

  // fragment LDS byte offsets (hoisted)
  int aoff[4], boff[4];
#pragma unroll
  for (int m = 0; m < 4; m++) {
    int rowl = wr * 64 + m * 16 + l15;
    aoff[m] = rowl * 64 + ((khalf * 16) ^ ((rowl & 3) << 4));
  }
#pragma unroll
  for (int n = 0; n < 4; n++) {
    int coll = wc * 64 + n * 16 + l15;
    if constexpr (WB)
      boff[n] = coll * 64 + ((khalf * 16) ^ ((coll & 3) << 4));
    else
      boff[n] = coll * 128 + ((khalf * 32) ^ ((coll & 7) << 4));
  }

  fl4 acc[4][4];
#pragma unroll
  for (int m = 0; m < 4; m++)
#pragma unroll
    for (int n = 0; n < 4; n++) acc[m][n] = (fl4){0.f, 0.f, 0.f, 0.f};

  for (int kt = 0; kt < KTOT / 32; ++kt) {
#pragma unroll
    for (int r2 = 0; r2 < 2; r2++)
      gload_lds16(asrc[r2] + kt * 32, &As[(r2 * 256 + wv * 64) * 8]);
    if constexpr (WB) {
#pragma unroll
      for (int r2 = 0; r2 < 2; r2++)
        gload_lds16(bsrcb[r2] + kt * 32, Braw + (r2 * 256 + wv * 64) * 16);
    } else {
#pragma unroll
      for (int r4 = 0; r4 < 4; r4++)
        gload_lds16(bsrcf[r4] + kt * 32, Braw + (r4 * 256 + wv * 64) * 16);
    }
    __syncthreads();

    sh8 af[4], bfr[4];
#pragma unroll
    for (int m = 0; m < 4; m++)
      af[m] = *(const sh8*)((const char*)As + aoff[m]);
    if constexpr (WB) {
#pragma unroll
      for (int n = 0; n < 4; n++)
        bfr[n] = *(const sh8*)(Braw + boff[n]);
    } else {
#pragma unroll
      for (int n = 0; n < 4; n++) {
        int coll = wc * 64 + n * 16 + l15;
        int o1 = coll * 128 + ((khalf * 32 + 16) ^ ((coll & 7) << 4));
        fl4 b0 = *(const fl4*)(Braw + boff[n]);
        fl4 b1 = *(const fl4*)(Braw + o1);
        sh8 bv;
#pragma unroll
        for (int i = 0; i < 4; i++) {
          bv[i] = (short)f2bf(b0[i]);
          bv[i + 4] = (short)f2bf(b1[i]);
        }
        bfr[n] = bv;
      }
    }
#pragma unroll
    for (int m = 0; m < 4; m++)
#pragma unroll
      for (int n = 0; n < 4; n++)
        acc[m][n] = __builtin_amdgcn_mfma_f32_16x16x32_bf16(af[m], bfr[n], acc[m][n], 0, 0, 0);
    __syncthreads();
  }

  if (FC1) {
#pragma unroll
    for (int n = 0; n < 4; n++) {
      int colg = nt * 128 + wc * 64 + n * 16 + l15;
      float bn = bias[(size_t)e * DH + colg];
#pragma unroll
      for (int m = 0; m < 4; m++) {
#pragma unroll
        for (int j = 0; j < 4; j++) {
          int grow = mt * 128 + wr * 64 + m * 16 + khalf * 4 + j;
          if (grow < cnt) {
            float v = acc[m][n][j] + bn;
            Hout[(size_t)(base + grow) * DH + colg] = f2bf(gelu_tanh(v));
          }
        }
      }
    }
  } else {
#pragma unroll
    for (int m = 0; m < 4; m++) {
#pragma unroll
      for (int j = 0; j < 4; j++) {
        int grow = mt * 128 + wr * 64 + m * 16 + khalf * 4 + j;
        if (grow < cnt) {
          int slot = base + grow;
          int t = tok_map[slot];
          float w = pair_w[slot];
#pragma unroll
          for (int n = 0; n < 4; n++) {
            int colg = nt * 128 + wc * 64 + n * 16 + l15;
            float v = acc[m][n][j] + bias[(size_t)e * DM + colg];
            atomicAdd(&Out[(size_t)t * DM + colg], w * v);
          }
        }
      }
    }
  }
}

extern "C" void kernel_launch(void* const* d_in, const int* in_sizes, int n_in,
                              void* d_out, int out_size, void* d_ws, size_t ws_size,
                              hipStream_t stream) {
  const float* x  = (const float*)d_in[0];
  const float* rw = (const float*)d_in[1];
  const float* w1 = (const float*)d_in[2];
  const float* b1 = (const float*)d_in[3];
  const float* w2 = (const float*)d_in[4];
  const float* b2 = (const float*)d_in[5];
  float* out = (float*)d_out;

  char* ws = (char*)d_ws;
  size_t off = 0;
  u16* xbf = (u16*)(ws + off); off += (size_t)T_TOK * DM * 2;
  u16* H   = (u16*)(ws + off); off += (size_t)H_ROWS * DH * 2;
  size_t woff = off;
  size_t wbytes = WELEMS * 2;
  bool big = (ws_size >= woff + 2 * wbytes + (size_t)H_ROWS * 8 + (size_t)T_TOK * 16 + 128);
  u16 *w1b = nullptr, *w2b = nullptr;
  if (big) {
    w1b = (u16*)(ws + off); off += wbytes;
    w2b = (u16*)(ws + off); off += wbytes;
  }
  int* tok_map  = (int*)(ws + off); off += (size_t)H_ROWS * 4;
  float* pair_w = (float*)(ws + off); off += (size_t)H_ROWS * 4;
  int* tok_e    = (int*)(ws + off); off += (size_t)T_TOK * 8;
  float* tok_w  = (float*)(ws + off); off += (size_t)T_TOK * 8;
  int* ctl      = (int*)(ws + off); off += 96;

  hipMemsetAsync(out, 0, (size_t)T_TOK * DM * 4, stream);
  hipMemsetAsync(ctl, 0, 24 * 4, stream);

  router_kernel<<<T_TOK / 4, 256, 0, stream>>>(x, rw, xbf, tok_e, tok_w, ctl);
  scan_kernel<<<1, 64, 0, stream>>>(ctl);
  assign_kernel<<<(T_TOK + 128 + 255) / 256, 256, 0, stream>>>(tok_e, tok_w, ctl, tok_map, pair_w);

  if (big) {
    wconv_kernel<<<4096, 256, 0, stream>>>(w1, w2, w1b, w2b);
    moe_gemm<true, true><<<NE * 32 * (DH / 128), 256, 0, stream>>>(
        xbf, nullptr, w1b, b1, H, nullptr, tok_map, pair_w, ctl);
    moe_gemm<false, true><<<NE * 32 * (DM / 128), 256, 0, stream>>>(
        H, nullptr, w2b, b2, nullptr, out, tok_map, pair_w, ctl);
  } else {
    moe_gemm<true, false><<<NE * 32 * (DH / 128), 256, 0, stream>>>(
        xbf, w1, nullptr, b1, H, nullptr, tok_map, pair_w, ctl);
    moe_gemm<false, false><<<NE * 32 * (DM / 128), 256, 0, stream>>>(
        H, w2, nullptr, b2, nullptr, out, tok_map, pair_w, ctl);
  }
}